// Round 8
// baseline (570.821 us; speedup 1.0000x reference)
//
#include <hip/hip_runtime.h>
#include <hip/hip_bf16.h>
#include <hip/hip_cooperative_groups.h>

namespace cg = cooperative_groups;

#define N_NODES 20000
#define N_EDGES 32768
#define DIM 128
#define N_REL 474
#define N_BASIS 64
#define TILE_E 64
#define MAXCH (N_EDGES / TILE_E + N_REL)   // 986 upper bound on chunk count
#define WSTRIDE 260                         // LDS row stride (shorts) for wmix staging
#define NROOTW ((N_NODES + 63) / 64)        // 313 root work items
#define SMEM_BYTES 51712                    // max over phases (msg: wt+xjf+scf+sdd)

typedef __bf16 bf16x8 __attribute__((ext_vector_type(8)));
typedef float f32x4 __attribute__((ext_vector_type(4)));

// ---------- helpers ----------
__device__ __forceinline__ unsigned short f2b(float f) {   // RNE fp32 -> bf16 bits
    unsigned u = __float_as_uint(f);
    unsigned r = (u + 0x7FFFu + ((u >> 16) & 1u)) >> 16;
    return (unsigned short)r;
}
__device__ __forceinline__ float b2f(unsigned short s) {
    return __uint_as_float(((unsigned)s) << 16);
}
__device__ __forceinline__ __bf16 u2b(unsigned short u) {
    union { unsigned short u; __bf16 b; } c; c.u = u; return c.b;
}

struct MegaParams {
    const int* entity; const int* src; const int* dst; const int* etype;
    const float* emb;
    const float* basis1; const float* att1; const float* w1; const float* root1; const float* bias1;
    const float* basis2; const float* att2; const float* w2; const float* root2; const float* bias2;
    unsigned short* W; unsigned short* xb; unsigned short* hb;
    float* acc1; float* acc2; float* denom1; float* denom2; float* alpha;
    int* cnt; int* nchunks; int* offs; int* cursor; int* eids; int* chunk_r; int* chunk_o;
    float* out;
};

// ---------- P0: gather + count + zero acc ----------
__device__ void prep_work(const MegaParams& P, int gtid, int gsz) {
    const float4* emb = (const float4*)P.emb;
    ushort4* xb4 = (ushort4*)P.xb;
    int total4 = N_NODES * DIM / 4;
    for (int i = gtid; i < total4; i += gsz) {
        int n = i >> 5, rem = i & 31;
        float4 v = emb[(size_t)P.entity[n] * 32 + rem];
        ushort4 s;
        s.x = f2b(v.x); s.y = f2b(v.y); s.z = f2b(v.z); s.w = f2b(v.w);
        xb4[i] = s;
    }
    for (int e = gtid; e < N_EDGES; e += gsz) atomicAdd(&P.cnt[P.etype[e]], 1);
    float4 z = make_float4(0.f, 0.f, 0.f, 0.f);
    float4* accz = (float4*)P.acc1;            // acc1|acc2 contiguous
    int totz = 2 * N_NODES * DIM / 4;
    for (int i = gtid; i < totz; i += gsz) accz[i] = z;
}

// ---------- scan over R + chunk build (single block, 256 thr, 512 slots) ----------
__device__ void scan_work(const MegaParams& P, unsigned char* smem, int t) {
    int* s = (int*)smem;
    int v0 = (t < N_REL) ? P.cnt[t] : 0;
    int v1 = (t + 256 < N_REL) ? P.cnt[t + 256] : 0;
    s[t] = v0; s[t + 256] = v1;
    __syncthreads();
    for (int d = 1; d < 512; d <<= 1) {
        int a0 = (t >= d) ? s[t - d] : 0;
        int a1 = (t + 256 >= d) ? s[t + 256 - d] : 0;
        __syncthreads();
        s[t] += a0; s[t + 256] += a1;
        __syncthreads();
    }
    int e0 = s[t] - v0, e1 = s[t + 256] - v1;
    if (t < N_REL) { P.offs[t] = e0; P.cursor[t] = e0; }
    if (t + 256 < N_REL) { P.offs[t + 256] = e0 * 0 + e1; P.cursor[t + 256] = e1; }
    if (t == 0) P.offs[N_REL] = N_EDGES;
    if (t < N_REL && v0 > 0) {
        int nc = (v0 + TILE_E - 1) / TILE_E;
        int b = atomicAdd(P.nchunks, nc);
        for (int c = 0; c < nc; c++) { P.chunk_r[b + c] = t; P.chunk_o[b + c] = e0 + c * TILE_E; }
    }
    if (t + 256 < N_REL && v1 > 0) {
        int nc = (v1 + TILE_E - 1) / TILE_E;
        int b = atomicAdd(P.nchunks, nc);
        for (int c = 0; c < nc; c++) { P.chunk_r[b + c] = t + 256; P.chunk_o[b + c] = e1 + c * TILE_E; }
    }
}

// ---------- scatter edges into relation-CSR ----------
__device__ void scatter_work(const MegaParams& P, int gtid, int gsz) {
    for (int e = gtid; e < N_EDGES; e += gsz) {
        int p = atomicAdd(&P.cursor[P.etype[e]], 1);
        P.eids[p] = e;
    }
}

// ---------- fused logit+exp+denom (no max-shift: |logit| small at these scales) ----------
__device__ void logit_work(const unsigned short* xb, const float* w,
                           const int* src, const int* dst, const int* et,
                           float* alpha, float* den, int gtid, int gsz) {
    int lane = gtid & 63;
    int gw = gtid >> 6, nw = gsz >> 6;
    for (int e = gw; e < N_EDGES; e += nw) {
        int s = src[e], d = dst[e], r = et[e];
        unsigned ax = ((const unsigned*)(xb + (size_t)s * DIM))[lane];
        unsigned bx = ((const unsigned*)(xb + (size_t)d * DIM))[lane];
        float2 wv = ((const float2*)(w + (size_t)r * DIM))[lane];
        float v = b2f((unsigned short)(ax & 0xFFFF)) * wv.x * b2f((unsigned short)(bx & 0xFFFF))
                + b2f((unsigned short)(ax >> 16)) * wv.y * b2f((unsigned short)(bx >> 16));
        for (int o = 32; o > 0; o >>= 1) v += __shfl_xor(v, o, 64);
        if (lane == 0) {
            float a = expf(v);
            alpha[e] = a;
            atomicAdd(&den[d], a);
        }
    }
}

// ---------- W = att @ basis via MFMA (512 work items: 64 io-chunks x 8 r-tiles) ----------
__device__ void wmix_work(const float* att, const float* basis, unsigned short* W,
                          int start, int stride, unsigned char* smem, int t) {
    unsigned short* bt = (unsigned short*)smem;
    for (int wi = start; wi < 512; wi += stride) {
        int io0 = (wi & 63) * 256;
        int r0 = (wi >> 6) * 64;
        __syncthreads();
#pragma unroll
        for (int p = 0; p < 16; p++) {
            int c = t + 256 * p;
            int k = c >> 6, of = c & 63;
            float4 v = *(const float4*)(basis + (size_t)k * (DIM * DIM) + io0 + of * 4);
            ushort4 s;
            s.x = f2b(v.x); s.y = f2b(v.y); s.z = f2b(v.z); s.w = f2b(v.w);
            *(ushort4*)&bt[k * WSTRIDE + of * 4] = s;
        }
        __syncthreads();
        int w = t >> 6, l = t & 63, n = l & 15, q = l >> 4;
        f32x4 acc[4][4] = {};                   // [rt][c]
#pragma unroll
        for (int kb = 0; kb < 2; kb++) {
            int kbase = kb * 32 + q * 8;
            bf16x8 a[4];
#pragma unroll
            for (int rt = 0; rt < 4; rt++) {
                int rm = min(r0 + rt * 16 + n, N_REL - 1);
                const float* ap = att + (size_t)rm * N_BASIS + kbase;
#pragma unroll
                for (int j = 0; j < 8; j++) a[rt][j] = u2b(f2b(ap[j]));
            }
#pragma unroll
            for (int c = 0; c < 4; c++) {
                int ob = w * 64 + c * 16 + n;
                bf16x8 b;
#pragma unroll
                for (int j = 0; j < 8; j++) b[j] = u2b(bt[(kbase + j) * WSTRIDE + ob]);
#pragma unroll
                for (int rt = 0; rt < 4; rt++)
                    acc[rt][c] = __builtin_amdgcn_mfma_f32_16x16x32_bf16(a[rt], b, acc[rt][c], 0, 0, 0);
            }
        }
#pragma unroll
        for (int rt = 0; rt < 4; rt++) {
#pragma unroll
            for (int c = 0; c < 4; c++) {
                int col = io0 + w * 64 + c * 16 + n;
#pragma unroll
                for (int rg = 0; rg < 4; rg++) {
                    int r = r0 + rt * 16 + q * 4 + rg;
                    if (r < N_REL) W[(size_t)r * (DIM * DIM) + col] = f2b(acc[rt][c][rg]);
                }
            }
        }
    }
}

// ---------- msg: per 64-edge chunk, (64x128)@(128x128) MFMA + alpha-scaled atomicAdd ----------
__device__ void msg_work(const unsigned short* xb, const MegaParams& P,
                         const float* den, float* outacc, unsigned char* smem, int t) {
    unsigned short* wt = (unsigned short*)smem;                 // 128*136 shorts
    unsigned short* xjf = wt + 128 * 136;                       // 8192 shorts
    float* scf = (float*)(smem + (128 * 136 + 8192) * 2);       // 64 floats
    int* sdd = (int*)(smem + (128 * 136 + 8192) * 2 + 256);     // 64 ints
    int NC = *P.nchunks;
    for (int ch = blockIdx.x; ch < NC; ch += gridDim.x) {
        __syncthreads();
        int r = P.chunk_r[ch];
        int base = P.chunk_o[ch];
        int nE = min(TILE_E, P.offs[r + 1] - base);
        const unsigned short* Wr = P.W + (size_t)r * (DIM * DIM);
        if (t < TILE_E) {
            if (t < nE) {
                int e = P.eids[base + t];
                int d_ = P.dst[e];
                sdd[t] = d_;
                scf[t] = P.alpha[e] / den[d_];
            } else { sdd[t] = 0; scf[t] = 0.f; }
        }
#pragma unroll
        for (int p = 0; p < 4; p++) {
            int c = t + 256 * p;
            int g = c >> 6;
            int rt = g >> 2, kb = g & 3;
            int q = (c >> 4) & 3, m = c & 15;
            int e = rt * 16 + m;
            int oct = kb * 4 + q;
            int4 v = make_int4(0, 0, 0, 0);
            if (e < nE)
                v = *(const int4*)(xb + (size_t)P.src[P.eids[base + e]] * DIM + oct * 8);
            *(int4*)&xjf[c * 8] = v;
        }
#pragma unroll
        for (int p = 0; p < 8; p++) {
            int c = t + 256 * p;
            int k = c >> 4, oct = c & 15;
            int4 v = *(const int4*)(Wr + k * DIM + oct * 8);
            *(int4*)&wt[k * 136 + oct * 8] = v;
        }
        __syncthreads();

        int w = t >> 6, l = t & 63, n = l & 15, q = l >> 4;
        f32x4 acc[2][4] = {};
#pragma unroll
        for (int kb = 0; kb < 4; kb++) {
            bf16x8 a[4];
#pragma unroll
            for (int rt = 0; rt < 4; rt++) a[rt] = *(const bf16x8*)&xjf[((rt * 4 + kb) * 64 + l) * 8];
            int kbase = kb * 32 + q * 8;
#pragma unroll
            for (int c = 0; c < 2; c++) {
                int ob = (w * 2 + c) * 16 + n;
                bf16x8 b;
#pragma unroll
                for (int j = 0; j < 8; j++) b[j] = u2b(wt[(kbase + j) * 136 + ob]);
#pragma unroll
                for (int rt = 0; rt < 4; rt++)
                    acc[c][rt] = __builtin_amdgcn_mfma_f32_16x16x32_bf16(a[rt], b, acc[c][rt], 0, 0, 0);
            }
        }
#pragma unroll
        for (int c = 0; c < 2; c++) {
            int col = (w * 2 + c) * 16 + n;
#pragma unroll
            for (int rt = 0; rt < 4; rt++) {
#pragma unroll
                for (int rg = 0; rg < 4; rg++) {
                    int e = rt * 16 + q * 4 + rg;
                    if (e < nE)
                        atomicAdd(&outacc[(size_t)sdd[e] * DIM + col], scf[e] * acc[c][rt][rg]);
                }
            }
        }
    }
}

// ---------- root: out = acc + x @ root + bias via MFMA; mode 1 = relu+bf16, 0 = fp32 ----------
__device__ void root_work(const unsigned short* xb, const float* rootM, const float* bias,
                          const float* accbuf, unsigned short* outb, float* outf,
                          int mode, unsigned char* smem, int t) {
    unsigned short* wt = (unsigned short*)smem;
    unsigned short* xrf = wt + 128 * 136;
    for (int wb = blockIdx.x; wb < NROOTW; wb += gridDim.x) {
        __syncthreads();
        int n0 = wb * 64;
#pragma unroll
        for (int p = 0; p < 4; p++) {
            int c = t + 256 * p;
            int g = c >> 6;
            int rt = g >> 2, kb = g & 3;
            int q = (c >> 4) & 3, m = c & 15;
            int row = n0 + rt * 16 + m;
            int oct = kb * 4 + q;
            int4 v = make_int4(0, 0, 0, 0);
            if (row < N_NODES) v = *(const int4*)(xb + (size_t)row * DIM + oct * 8);
            *(int4*)&xrf[c * 8] = v;
        }
#pragma unroll
        for (int p = 0; p < 16; p++) {
            int c = t + 256 * p;
            int k = c >> 5, of = c & 31;
            float4 v = *(const float4*)(rootM + k * DIM + of * 4);
            ushort4 s;
            s.x = f2b(v.x); s.y = f2b(v.y); s.z = f2b(v.z); s.w = f2b(v.w);
            *(ushort4*)&wt[k * 136 + of * 4] = s;
        }
        __syncthreads();

        int w = t >> 6, l = t & 63, n = l & 15, q = l >> 4;
        f32x4 acc[2][4] = {};
#pragma unroll
        for (int kb = 0; kb < 4; kb++) {
            bf16x8 a[4];
#pragma unroll
            for (int rt = 0; rt < 4; rt++) a[rt] = *(const bf16x8*)&xrf[((rt * 4 + kb) * 64 + l) * 8];
            int kbase = kb * 32 + q * 8;
#pragma unroll
            for (int c = 0; c < 2; c++) {
                int ob = (w * 2 + c) * 16 + n;
                bf16x8 b;
#pragma unroll
                for (int j = 0; j < 8; j++) b[j] = u2b(wt[(kbase + j) * 136 + ob]);
#pragma unroll
                for (int rt = 0; rt < 4; rt++)
                    acc[c][rt] = __builtin_amdgcn_mfma_f32_16x16x32_bf16(a[rt], b, acc[c][rt], 0, 0, 0);
            }
        }
#pragma unroll
        for (int c = 0; c < 2; c++) {
            int col = (w * 2 + c) * 16 + n;
            float bo = bias[col];
#pragma unroll
            for (int rt = 0; rt < 4; rt++) {
#pragma unroll
                for (int rg = 0; rg < 4; rg++) {
                    int row = n0 + rt * 16 + q * 4 + rg;
                    if (row < N_NODES) {
                        float v = accbuf[(size_t)row * DIM + col] + acc[c][rt][rg] + bo;
                        if (mode) {
                            outb[(size_t)row * DIM + col] = f2b(fmaxf(v, 0.f));
                        } else {
                            outf[(size_t)row * DIM + col] = v;
                        }
                    }
                }
            }
        }
    }
}

// ---------- the mega kernel: whole model, 8 phases, 7 grid syncs ----------
__global__ __launch_bounds__(256, 3) void mega_kernel(MegaParams P) {
    cg::grid_group grid = cg::this_grid();
    __shared__ __align__(16) unsigned char smem[SMEM_BYTES];
    const int t = threadIdx.x;
    const int gtid = blockIdx.x * 256 + t;
    const int gsz = gridDim.x * 256;

    // P0: gather + count + zero acc1/acc2
    prep_work(P, gtid, gsz);
    grid.sync();

    // P1: block 0 scans relations + builds chunks; others compute W1
    if (blockIdx.x == 0) {
        scan_work(P, smem, t);
        if (gridDim.x == 1) wmix_work(P.att1, P.basis1, P.W, 0, 1, smem, t);
    } else {
        wmix_work(P.att1, P.basis1, P.W, blockIdx.x - 1, gridDim.x - 1, smem, t);
    }
    grid.sync();

    // P2: scatter + logit1 (independent)
    scatter_work(P, gtid, gsz);
    logit_work(P.xb, P.w1, P.src, P.dst, P.etype, P.alpha, P.denom1, gtid, gsz);
    grid.sync();

    // P3: msg1 -> acc1
    msg_work(P.xb, P, P.denom1, P.acc1, smem, t);
    grid.sync();

    // P4: root1 -> hb (relu, bf16)
    root_work(P.xb, P.root1, P.bias1, P.acc1, P.hb, nullptr, 1, smem, t);
    grid.sync();

    // P5: wmix2 + logit2
    wmix_work(P.att2, P.basis2, P.W, blockIdx.x, gridDim.x, smem, t);
    logit_work(P.hb, P.w2, P.src, P.dst, P.etype, P.alpha, P.denom2, gtid, gsz);
    grid.sync();

    // P6: msg2 -> acc2
    msg_work(P.hb, P, P.denom2, P.acc2, smem, t);
    grid.sync();

    // P7: root2 -> out (fp32)
    root_work(P.hb, P.root2, P.bias2, P.acc2, nullptr, P.out, 0, smem, t);
}

extern "C" void kernel_launch(void* const* d_in, const int* in_sizes, int n_in,
                              void* d_out, int out_size, void* d_ws, size_t ws_size,
                              hipStream_t stream) {
    const int N = N_NODES, E = N_EDGES, R = N_REL;

    const int* eidx = (const int*)d_in[1];

    size_t off = 0;
    auto alloc = [&](size_t bytes) -> void* {
        void* p = (char*)d_ws + off;
        off += (bytes + 255) & ~(size_t)255;
        return p;
    };
    unsigned short* W  = (unsigned short*)alloc((size_t)R * DIM * DIM * 2);
    unsigned short* xb = (unsigned short*)alloc((size_t)N * DIM * 2);
    unsigned short* hb = (unsigned short*)alloc((size_t)N * DIM * 2);
    float* accpair     = (float*)alloc((size_t)2 * N * DIM * 4);   // acc1 | acc2 (contiguous)
    float* alpha       = (float*)alloc((size_t)E * 4);
    // zeroed meta region: cnt[R] | nchunks[1] | denom1[N] | denom2[N]
    int* meta          = (int*)alloc((size_t)(R + 1 + 2 * N) * 4);
    int* offs          = (int*)alloc((size_t)(R + 1) * 4);
    int* cursor        = (int*)alloc((size_t)R * 4);
    int* eids          = (int*)alloc((size_t)E * 4);
    int* chunk_r       = (int*)alloc((size_t)MAXCH * 4);
    int* chunk_o       = (int*)alloc((size_t)MAXCH * 4);

    MegaParams P;
    P.entity = (const int*)d_in[0];
    P.src    = eidx;
    P.dst    = eidx + E;
    P.etype  = (const int*)d_in[2];
    P.emb    = (const float*)d_in[3];
    P.basis1 = (const float*)d_in[4];
    P.att1   = (const float*)d_in[5];
    P.w1     = (const float*)d_in[6];
    P.root1  = (const float*)d_in[7];
    P.bias1  = (const float*)d_in[8];
    P.basis2 = (const float*)d_in[9];
    P.att2   = (const float*)d_in[10];
    P.w2     = (const float*)d_in[11];
    P.root2  = (const float*)d_in[12];
    P.bias2  = (const float*)d_in[13];
    P.W = W; P.xb = xb; P.hb = hb;
    P.acc1 = accpair; P.acc2 = accpair + (size_t)N * DIM;
    P.denom1 = (float*)(meta + R + 1);
    P.denom2 = (float*)(meta + R + 1 + N);
    P.alpha = alpha;
    P.cnt = meta; P.nchunks = meta + R;
    P.offs = offs; P.cursor = cursor; P.eids = eids;
    P.chunk_r = chunk_r; P.chunk_o = chunk_o;
    P.out = (float*)d_out;

    // zero cnt|nchunks|denom1|denom2 (~162 KB)
    hipMemsetAsync(meta, 0, (size_t)(R + 1 + 2 * N) * 4, stream);

    int nb = 0;
    hipOccupancyMaxActiveBlocksPerMultiprocessor(&nb, mega_kernel, 256, 0);
    if (nb < 1) nb = 1;
    if (nb > 3) nb = 3;            // LDS-bound ceiling anyway (51.7 KB/block)
    int grid = 256 * nb;           // 256 CUs on gfx950

    void* args[] = { (void*)&P };
    hipLaunchCooperativeKernel((void*)mega_kernel, dim3(grid), dim3(256), args, 0, stream);
}

// Round 10
// 247.359 us; speedup vs baseline: 2.3077x; 2.3077x over previous
//
#include <hip/hip_runtime.h>
#include <hip/hip_bf16.h>

#define N_NODES 20000
#define N_EDGES 32768
#define DIM 128
#define N_REL 474
#define N_BASIS 64
#define TILE_E 64
#define MAXCH (N_EDGES / TILE_E + N_REL)   // 986 upper bound on chunk count
#define WSTRIDE 260                         // LDS row stride (shorts) for wmix staging

typedef __bf16 bf16x8 __attribute__((ext_vector_type(8)));
typedef float f32x4 __attribute__((ext_vector_type(4)));

// ---------- helpers ----------
__device__ __forceinline__ unsigned short f2b(float f) {   // RNE fp32 -> bf16 bits
    unsigned u = __float_as_uint(f);
    unsigned r = (u + 0x7FFFu + ((u >> 16) & 1u)) >> 16;
    return (unsigned short)r;
}
__device__ __forceinline__ float b2f(unsigned short s) {
    return __uint_as_float(((unsigned)s) << 16);
}
__device__ __forceinline__ __bf16 u2b(unsigned short u) {
    union { unsigned short u; __bf16 b; } c; c.u = u; return c.b;
}

// ---------- prep: gather xb = bf16(emb[entity]) + count etype + zero acc/denom ----------
__global__ __launch_bounds__(256) void prep_kernel(const float4* __restrict__ emb,
                                                   const int* __restrict__ entity,
                                                   const int* __restrict__ etype,
                                                   ushort4* __restrict__ xb4,
                                                   float4* __restrict__ zreg, int zcount4,
                                                   int* __restrict__ cnt) {
    int gtid = blockIdx.x * 256 + threadIdx.x;
    int gsz = gridDim.x * 256;
    int total4 = N_NODES * DIM / 4;
    for (int i = gtid; i < total4; i += gsz) {
        int n = i >> 5, rem = i & 31;
        float4 v = emb[(size_t)entity[n] * 32 + rem];
        ushort4 s;
        s.x = f2b(v.x); s.y = f2b(v.y); s.z = f2b(v.z); s.w = f2b(v.w);
        xb4[i] = s;
    }
    for (int e = gtid; e < N_EDGES; e += gsz) atomicAdd(&cnt[etype[e]], 1);
    float4 z = make_float4(0.f, 0.f, 0.f, 0.f);
    for (int i = gtid; i < zcount4; i += gsz) zreg[i] = z;
}

// ---------- scan over R + emit (relation, 64-edge-chunk) work list (R7-proven) ----------
__global__ void scanr_kernel(const int* __restrict__ cnt, int* __restrict__ offs,
                             int* __restrict__ cursor, int* __restrict__ chunk_r,
                             int* __restrict__ chunk_o, int* __restrict__ nchunks,
                             int R, int E) {
    __shared__ int s[512];
    int t = threadIdx.x;
    int v = (t < R) ? cnt[t] : 0;
    s[t] = v;
    __syncthreads();
    for (int d = 1; d < 512; d <<= 1) {
        int add = (t >= d) ? s[t - d] : 0;
        __syncthreads();
        s[t] += add;
        __syncthreads();
    }
    int excl = s[t] - v;
    if (t < R) { offs[t] = excl; cursor[t] = excl; }
    if (t == 0) offs[R] = E;
    int nc = (v + TILE_E - 1) / TILE_E;
    if (t < R && nc > 0) {
        int b = atomicAdd(nchunks, nc);
        for (int c = 0; c < nc; c++) { chunk_r[b + c] = t; chunk_o[b + c] = excl + c * TILE_E; }
    }
}

__global__ void scatter_kernel(const int* __restrict__ et, int* __restrict__ cursor,
                               int* __restrict__ eids, int E) {
    int e = blockIdx.x * blockDim.x + threadIdx.x;
    if (e < E) {
        int p = atomicAdd(&cursor[et[e]], 1);
        eids[p] = e;
    }
}

// ---------- fused logit + exp + denom (no max-shift; |logit| <~ 3 here, fp32-safe) ----------
__global__ __launch_bounds__(256) void logitexp_kernel(const unsigned short* __restrict__ xb,
                                                       const float* __restrict__ w,
                                                       const int* __restrict__ src,
                                                       const int* __restrict__ dst,
                                                       const int* __restrict__ et,
                                                       float* __restrict__ alpha,
                                                       float* __restrict__ den, int E) {
    int wid = (blockIdx.x * 256 + threadIdx.x) >> 6;
    int lane = threadIdx.x & 63;
    if (wid >= E) return;
    int s = src[wid], d = dst[wid], r = et[wid];
    unsigned ax = ((const unsigned*)(xb + (size_t)s * DIM))[lane];
    unsigned bx = ((const unsigned*)(xb + (size_t)d * DIM))[lane];
    float2 wv = ((const float2*)(w + (size_t)r * DIM))[lane];
    float v = b2f((unsigned short)(ax & 0xFFFF)) * wv.x * b2f((unsigned short)(bx & 0xFFFF))
            + b2f((unsigned short)(ax >> 16)) * wv.y * b2f((unsigned short)(bx >> 16));
    for (int off = 32; off > 0; off >>= 1) v += __shfl_xor(v, off, 64);
    if (lane == 0) {
        float a = expf(v);
        alpha[wid] = a;
        atomicAdd(&den[d], a);
    }
}

// ---------- W = att @ basis via MFMA: [R,64] @ [64, D*D] -> bf16 (R7-proven) ----------
__global__ __launch_bounds__(256) void wmix_kernel(const float* __restrict__ att,
                                                   const float* __restrict__ basis,
                                                   unsigned short* __restrict__ W, int R) {
    int io0 = blockIdx.x * 256;
    int r0 = blockIdx.y * 64;
    __shared__ unsigned short bt[64 * WSTRIDE];
    int t = threadIdx.x;
#pragma unroll
    for (int p = 0; p < 16; p++) {
        int c = t + 256 * p;
        int k = c >> 6, of = c & 63;
        float4 v = *(const float4*)(basis + (size_t)k * (DIM * DIM) + io0 + of * 4);
        ushort4 s;
        s.x = f2b(v.x); s.y = f2b(v.y); s.z = f2b(v.z); s.w = f2b(v.w);
        *(ushort4*)&bt[k * WSTRIDE + of * 4] = s;
    }
    __syncthreads();

    int w = t >> 6, l = t & 63, n = l & 15, q = l >> 4;
    f32x4 acc[4][4] = {};                       // [rt][c]
#pragma unroll
    for (int kb = 0; kb < 2; kb++) {
        int kbase = kb * 32 + q * 8;
        bf16x8 a[4];
#pragma unroll
        for (int rt = 0; rt < 4; rt++) {
            int rm = min(r0 + rt * 16 + n, R - 1);
            const float* ap = att + (size_t)rm * N_BASIS + kbase;
#pragma unroll
            for (int j = 0; j < 8; j++) a[rt][j] = u2b(f2b(ap[j]));
        }
#pragma unroll
        for (int c = 0; c < 4; c++) {
            int ob = w * 64 + c * 16 + n;
            bf16x8 b;
#pragma unroll
            for (int j = 0; j < 8; j++) b[j] = u2b(bt[(kbase + j) * WSTRIDE + ob]);
#pragma unroll
            for (int rt = 0; rt < 4; rt++)
                acc[rt][c] = __builtin_amdgcn_mfma_f32_16x16x32_bf16(a[rt], b, acc[rt][c], 0, 0, 0);
        }
    }
#pragma unroll
    for (int rt = 0; rt < 4; rt++) {
#pragma unroll
        for (int c = 0; c < 4; c++) {
            int col = io0 + w * 64 + c * 16 + n;
#pragma unroll
            for (int rg = 0; rg < 4; rg++) {
                int r = r0 + rt * 16 + q * 4 + rg;
                if (r < R) W[(size_t)r * (DIM * DIM) + col] = f2b(acc[rt][c][rg]);
            }
        }
    }
}

// ---------- msg: per 64-edge chunk, (64x128)@(128x128) MFMA + alpha-scaled atomicAdd (R7-proven) ----------
__global__ __launch_bounds__(256) void msg_kernel(const unsigned short* __restrict__ xb,
                                                  const unsigned short* __restrict__ W,
                                                  const int* __restrict__ chunk_r,
                                                  const int* __restrict__ chunk_off,
                                                  const int* __restrict__ nchunks,
                                                  const int* __restrict__ eids,
                                                  const int* __restrict__ offs,
                                                  const int* __restrict__ src,
                                                  const int* __restrict__ dst,
                                                  const float* __restrict__ ae,
                                                  const float* __restrict__ denom,
                                                  float* __restrict__ outacc) {
    if ((int)blockIdx.x >= *nchunks) return;
    int r = chunk_r[blockIdx.x];
    int base = chunk_off[blockIdx.x];
    int nE = min(TILE_E, offs[r + 1] - base);
    const unsigned short* Wr = W + (size_t)r * (DIM * DIM);

    __shared__ unsigned short wt[128 * 136];   // [k][o] pad
    __shared__ unsigned short xjf[8192];       // A-frag order, 64 edges
    __shared__ float scf[TILE_E];
    __shared__ int sdd[TILE_E];

    int t = threadIdx.x;
    if (t < TILE_E) {
        if (t < nE) {
            int e = eids[base + t];
            int d_ = dst[e];
            sdd[t] = d_;
            scf[t] = ae[e] / denom[d_];
        } else { sdd[t] = 0; scf[t] = 0.f; }
    }
    // stage A: slot c = (rt*4+kb)*64 + q*16 + m
#pragma unroll
    for (int p = 0; p < 4; p++) {
        int c = t + 256 * p;
        int g = c >> 6;
        int rt = g >> 2, kb = g & 3;
        int q = (c >> 4) & 3, m = c & 15;
        int e = rt * 16 + m;
        int oct = kb * 4 + q;
        int4 v = make_int4(0, 0, 0, 0);
        if (e < nE)
            v = *(const int4*)(xb + (size_t)src[eids[base + e]] * DIM + oct * 8);
        *(int4*)&xjf[c * 8] = v;
    }
    // stage W tile
#pragma unroll
    for (int p = 0; p < 8; p++) {
        int c = t + 256 * p;
        int k = c >> 4, oct = c & 15;
        int4 v = *(const int4*)(Wr + k * DIM + oct * 8);
        *(int4*)&wt[k * 136 + oct * 8] = v;
    }
    __syncthreads();

    int w = t >> 6, l = t & 63, n = l & 15, q = l >> 4;
    f32x4 acc[2][4] = {};                       // [ct-local][rt]
#pragma unroll
    for (int kb = 0; kb < 4; kb++) {
        bf16x8 a[4];
#pragma unroll
        for (int rt = 0; rt < 4; rt++) a[rt] = *(const bf16x8*)&xjf[((rt * 4 + kb) * 64 + l) * 8];
        int kbase = kb * 32 + q * 8;
#pragma unroll
        for (int c = 0; c < 2; c++) {
            int ob = (w * 2 + c) * 16 + n;
            bf16x8 b;
#pragma unroll
            for (int j = 0; j < 8; j++) b[j] = u2b(wt[(kbase + j) * 136 + ob]);
#pragma unroll
            for (int rt = 0; rt < 4; rt++)
                acc[c][rt] = __builtin_amdgcn_mfma_f32_16x16x32_bf16(a[rt], b, acc[c][rt], 0, 0, 0);
        }
    }
#pragma unroll
    for (int c = 0; c < 2; c++) {
        int col = (w * 2 + c) * 16 + n;
#pragma unroll
        for (int rt = 0; rt < 4; rt++) {
#pragma unroll
            for (int rg = 0; rg < 4; rg++) {
                int e = rt * 16 + q * 4 + rg;
                if (e < nE)
                    atomicAdd(&outacc[(size_t)sdd[e] * DIM + col], scf[e] * acc[c][rt][rg]);
            }
        }
    }
}

// ---------- root: out = acc + x @ root + bias via MFMA; mode 1 = relu+bf16, 0 = fp32 (R7-proven) ----------
__global__ __launch_bounds__(256) void root_kernel(const unsigned short* __restrict__ xb,
                                                   const float* __restrict__ rootM,
                                                   const float* __restrict__ bias,
                                                   const float* __restrict__ accbuf,
                                                   unsigned short* __restrict__ outb,
                                                   float* __restrict__ outf,
                                                   int mode, int N) {
    int n0 = blockIdx.x * 64;
    __shared__ unsigned short wt[128 * 136];
    __shared__ unsigned short xrf[8192];
    int t = threadIdx.x;
#pragma unroll
    for (int p = 0; p < 4; p++) {
        int c = t + 256 * p;
        int g = c >> 6;
        int rt = g >> 2, kb = g & 3;
        int q = (c >> 4) & 3, m = c & 15;
        int row = n0 + rt * 16 + m;
        int oct = kb * 4 + q;
        int4 v = make_int4(0, 0, 0, 0);
        if (row < N) v = *(const int4*)(xb + (size_t)row * DIM + oct * 8);
        *(int4*)&xrf[c * 8] = v;
    }
#pragma unroll
    for (int p = 0; p < 16; p++) {
        int c = t + 256 * p;
        int k = c >> 5, of = c & 31;
        float4 v = *(const float4*)(rootM + k * DIM + of * 4);
        ushort4 s;
        s.x = f2b(v.x); s.y = f2b(v.y); s.z = f2b(v.z); s.w = f2b(v.w);
        *(ushort4*)&wt[k * 136 + of * 4] = s;
    }
    __syncthreads();

    int w = t >> 6, l = t & 63, n = l & 15, q = l >> 4;
    f32x4 acc[2][4] = {};
#pragma unroll
    for (int kb = 0; kb < 4; kb++) {
        bf16x8 a[4];
#pragma unroll
        for (int rt = 0; rt < 4; rt++) a[rt] = *(const bf16x8*)&xrf[((rt * 4 + kb) * 64 + l) * 8];
        int kbase = kb * 32 + q * 8;
#pragma unroll
        for (int c = 0; c < 2; c++) {
            int ob = (w * 2 + c) * 16 + n;
            bf16x8 b;
#pragma unroll
            for (int j = 0; j < 8; j++) b[j] = u2b(wt[(kbase + j) * 136 + ob]);
#pragma unroll
            for (int rt = 0; rt < 4; rt++)
                acc[c][rt] = __builtin_amdgcn_mfma_f32_16x16x32_bf16(a[rt], b, acc[c][rt], 0, 0, 0);
        }
    }
#pragma unroll
    for (int c = 0; c < 2; c++) {
        int col = (w * 2 + c) * 16 + n;
        float bo = bias[col];
#pragma unroll
        for (int rt = 0; rt < 4; rt++) {
#pragma unroll
            for (int rg = 0; rg < 4; rg++) {
                int row = n0 + rt * 16 + q * 4 + rg;
                if (row < N) {
                    float v = accbuf[(size_t)row * DIM + col] + acc[c][rt][rg] + bo;
                    if (mode) {
                        outb[(size_t)row * DIM + col] = f2b(fmaxf(v, 0.f));
                    } else {
                        outf[(size_t)row * DIM + col] = v;
                    }
                }
            }
        }
    }
}

extern "C" void kernel_launch(void* const* d_in, const int* in_sizes, int n_in,
                              void* d_out, int out_size, void* d_ws, size_t ws_size,
                              hipStream_t stream) {
    const int N = N_NODES, E = N_EDGES, R = N_REL;

    const int* entity = (const int*)d_in[0];
    const int* eidx   = (const int*)d_in[1];
    const int* src    = eidx;
    const int* dst    = eidx + E;
    const int* etype  = (const int*)d_in[2];
    const float* emb  = (const float*)d_in[3];
    const float* basis1 = (const float*)d_in[4];
    const float* att1   = (const float*)d_in[5];
    const float* w1     = (const float*)d_in[6];
    const float* root1  = (const float*)d_in[7];
    const float* bias1  = (const float*)d_in[8];
    const float* basis2 = (const float*)d_in[9];
    const float* att2   = (const float*)d_in[10];
    const float* w2     = (const float*)d_in[11];
    const float* root2  = (const float*)d_in[12];
    const float* bias2  = (const float*)d_in[13];
    float* out = (float*)d_out;

    size_t off = 0;
    auto alloc = [&](size_t bytes) -> void* {
        void* p = (char*)d_ws + off;
        off += (bytes + 255) & ~(size_t)255;
        return p;
    };
    unsigned short* W  = (unsigned short*)alloc((size_t)R * DIM * DIM * 2);
    unsigned short* xb = (unsigned short*)alloc((size_t)N * DIM * 2);
    unsigned short* hb = (unsigned short*)alloc((size_t)N * DIM * 2);
    // contiguous zero region: acc1 | acc2 | denom1 | denom2
    float* zreg   = (float*)alloc((size_t)(2 * N * DIM + 2 * N) * 4);
    float* acc1   = zreg;
    float* acc2   = zreg + (size_t)N * DIM;
    float* denom1 = zreg + (size_t)2 * N * DIM;
    float* denom2 = denom1 + N;
    float* alpha  = (float*)alloc((size_t)E * 4);
    int* meta     = (int*)alloc((size_t)(R + 1) * 4);   // cnt | nchunks
    int* cnt      = meta;
    int* nchunks  = meta + R;
    int* offs     = (int*)alloc((size_t)(R + 1) * 4);
    int* cursor   = (int*)alloc((size_t)R * 4);
    int* eids     = (int*)alloc((size_t)E * 4);
    int* chunk_r  = (int*)alloc((size_t)MAXCH * 4);
    int* chunk_o  = (int*)alloc((size_t)MAXCH * 4);

    int zcount4 = (2 * N * DIM + 2 * N) / 4;

    // ---- prep (4 dispatches) ----
    hipMemsetAsync(meta, 0, (size_t)(R + 1) * 4, stream);
    prep_kernel<<<2048, 256, 0, stream>>>((const float4*)emb, entity, etype,
                                          (ushort4*)xb, (float4*)zreg, zcount4, cnt);
    scanr_kernel<<<1, 512, 0, stream>>>(cnt, offs, cursor, chunk_r, chunk_o, nchunks, R, E);
    scatter_kernel<<<(E + 255) / 256, 256, 0, stream>>>(etype, cursor, eids, E);

    // ---- layer 1: xb -> hb (relu, bf16) ----
    logitexp_kernel<<<E / 4, 256, 0, stream>>>(xb, w1, src, dst, etype, alpha, denom1, E);
    wmix_kernel<<<dim3(64, 8), 256, 0, stream>>>(att1, basis1, W, R);
    msg_kernel<<<MAXCH, 256, 0, stream>>>(xb, W, chunk_r, chunk_o, nchunks,
                                          eids, offs, src, dst, alpha, denom1, acc1);
    root_kernel<<<(N + 63) / 64, 256, 0, stream>>>(xb, root1, bias1, acc1, hb, nullptr, 1, N);

    // ---- layer 2: hb -> out (fp32) ----
    logitexp_kernel<<<E / 4, 256, 0, stream>>>(hb, w2, src, dst, etype, alpha, denom2, E);
    wmix_kernel<<<dim3(64, 8), 256, 0, stream>>>(att2, basis2, W, R);
    msg_kernel<<<MAXCH, 256, 0, stream>>>(hb, W, chunk_r, chunk_o, nchunks,
                                          eids, offs, src, dst, alpha, denom2, acc2);
    root_kernel<<<(N + 63) / 64, 256, 0, stream>>>(hb, root2, bias2, acc2, nullptr, out, 0, N);
}